// Round 4
// baseline (54.253 us; speedup 1.0000x reference)
//
#include <hip/hip_runtime.h>
#include <hip/hip_bf16.h>

typedef float f32x4 __attribute__((ext_vector_type(4)));
typedef short s16x8 __attribute__((ext_vector_type(8)));

constexpr int D  = 128;
constexpr int K  = 512;
constexpr int O  = 256;
constexpr int NT = 256;   // 4 waves
constexpr int PP = 40;    // Ps row stride (ushorts); 80B rows keep b128 reads 16B-aligned

__device__ __forceinline__ short bfhi(float f) {
    return (short)__builtin_bit_cast(ushort, __float2bfloat16(f));
}
__device__ __forceinline__ float bff(short h) {
    return __builtin_bit_cast(float, ((uint)(ushort)h) << 16);
}

__global__ __launch_bounds__(NT, 2)
void rbf_one(const float* __restrict__ x, const float* __restrict__ cen,
             const float* __restrict__ ls, const float* __restrict__ w,
             float* __restrict__ out)
{
    __shared__ ushort Ps[2][4][16][PP];   // [parity][wave][n][k_local]
    __shared__ float  Acc[2][16][O + 4];  // two combine buffers
    __shared__ float  Ls[4][16];          // per-wave row sums

    const int t    = threadIdx.x;
    const int lane = t & 63;
    const int wv   = t >> 6;     // 0..3  (owns K-quarter wv)
    const int l15  = lane & 15;
    const int l4   = lane >> 4;  // 0..3
    const int nb   = blockIdx.x * 16;

    // ---- X fragments (hoisted, invariant over k) + row norms ----
    s16x8 xh[4], xl[4];
    float sx = 0.f;
    {
        const float* xr = x + (size_t)(nb + l15) * D;
#pragma unroll
        for (int q = 0; q < 4; ++q) {
            float4 v0 = *(const float4*)(xr + q * 32 + l4 * 8);
            float4 v1 = *(const float4*)(xr + q * 32 + l4 * 8 + 4);
            float f[8] = {v0.x, v0.y, v0.z, v0.w, v1.x, v1.y, v1.z, v1.w};
            s16x8 h, lo;
#pragma unroll
            for (int j = 0; j < 8; ++j) {
                sx = fmaf(f[j], f[j], sx);
                short hb = bfhi(f[j]);
                h[j]  = hb;
                lo[j] = bfhi(f[j] - bff(hb));
            }
            xh[q] = h; xl[q] = lo;
        }
    }
    sx += __shfl_xor(sx, 16);
    sx += __shfl_xor(sx, 32);          // all lanes: ||x_{l15}||^2
    float xs2v[4];
#pragma unroll
    for (int r = 0; r < 4; ++r) xs2v[r] = __shfl(sx, l4 * 4 + r);

    f32x4 oacc[16];
#pragma unroll
    for (int ot = 0; ot < 16; ++ot) oacc[ot] = (f32x4){0.f, 0.f, 0.f, 0.f};
    float Lp[4] = {0.f, 0.f, 0.f, 0.f};

    const int kq = wv * (K / 4);       // this wave's kernel-quarter base

    // ---- main loop: 4 slabs of 32 kernels, no barriers ----
#pragma unroll
    for (int s = 0; s < 4; ++s) {
        const int k0 = kq + s * 32;

        // GEMM1 + exp for two 16-kernel tiles
#pragma unroll
        for (int bt = 0; bt < 2; ++bt) {
            const int kk = k0 + bt * 16 + l15;
            const float* cr = cen + (size_t)kk * D;
            s16x8 ch[4], cl[4];
            float sc = 0.f;
#pragma unroll
            for (int q = 0; q < 4; ++q) {
                float4 v0 = *(const float4*)(cr + q * 32 + l4 * 8);
                float4 v1 = *(const float4*)(cr + q * 32 + l4 * 8 + 4);
                float f[8] = {v0.x, v0.y, v0.z, v0.w, v1.x, v1.y, v1.z, v1.w};
                s16x8 h, lo;
#pragma unroll
                for (int j = 0; j < 8; ++j) {
                    sc = fmaf(f[j], f[j], sc);
                    short hb = bfhi(f[j]);
                    h[j]  = hb;
                    lo[j] = bfhi(f[j] - bff(hb));
                }
                ch[q] = h; cl[q] = lo;
            }
            sc += __shfl_xor(sc, 16);
            sc += __shfl_xor(sc, 32);  // ||c_kk||^2 in all lanes
            float es_ = __expf(2.0f * ls[kk]);

            // split-bf16 product: three independent 4-chains
            f32x4 ghh = (f32x4){0.f,0.f,0.f,0.f};
            f32x4 ghl = (f32x4){0.f,0.f,0.f,0.f};
            f32x4 glh = (f32x4){0.f,0.f,0.f,0.f};
#pragma unroll
            for (int q = 0; q < 4; ++q) {
                ghh = __builtin_amdgcn_mfma_f32_16x16x32_bf16(xh[q], ch[q], ghh, 0, 0, 0);
                ghl = __builtin_amdgcn_mfma_f32_16x16x32_bf16(xh[q], cl[q], ghl, 0, 0, 0);
                glh = __builtin_amdgcn_mfma_f32_16x16x32_bf16(xl[q], ch[q], glh, 0, 0, 0);
            }
            f32x4 gg = ghh + ghl + glh;

#pragma unroll
            for (int r = 0; r < 4; ++r) {
                float r2 = xs2v[r] + sc - 2.0f * gg[r];
                float ph = __expf(-es_ * r2);
                Lp[r] += ph;                       // (n=l4*4+r, summed over kk=l15 later)
                Ps[s & 1][wv][l4 * 4 + r][bt * 16 + l15] = (ushort)bfhi(ph);
            }
        }

        // wave-private transpose read (same-wave DS ordering, no barrier)
        s16x8 pa = *(const s16x8*)&Ps[s & 1][wv][l15][l4 * 8];

        // GEMM2: full O per wave over this slab's 32 kernels
#pragma unroll
        for (int ot = 0; ot < 16; ++ot) {
            const float* wr = w + (size_t)(ot * 16 + l15) * K + k0;
            float4 v0 = *(const float4*)(wr + l4 * 8);
            float4 v1 = *(const float4*)(wr + l4 * 8 + 4);
            s16x8 b;
            b[0] = bfhi(v0.x); b[1] = bfhi(v0.y); b[2] = bfhi(v0.z); b[3] = bfhi(v0.w);
            b[4] = bfhi(v1.x); b[5] = bfhi(v1.y); b[6] = bfhi(v1.z); b[7] = bfhi(v1.w);
            oacc[ot] = __builtin_amdgcn_mfma_f32_16x16x32_bf16(pa, b, oacc[ot], 0, 0, 0);
        }
    }

    // ---- row-sum reduce over the 16 kk-lanes ----
#pragma unroll
    for (int r = 0; r < 4; ++r) {
        float v = Lp[r];
        v += __shfl_xor(v, 1); v += __shfl_xor(v, 2);
        v += __shfl_xor(v, 4); v += __shfl_xor(v, 8);
        if (l15 == 0) Ls[wv][l4 * 4 + r] = v;
    }

    // ---- combine 4 wave-partials (only barriers in the kernel) ----
    if (wv < 2) {
#pragma unroll
        for (int ot = 0; ot < 16; ++ot)
#pragma unroll
            for (int r = 0; r < 4; ++r)
                Acc[wv][l4 * 4 + r][ot * 16 + l15] = oacc[ot][r];
    }
    __syncthreads();
    if (wv >= 2) {
#pragma unroll
        for (int ot = 0; ot < 16; ++ot)
#pragma unroll
            for (int r = 0; r < 4; ++r)
                Acc[wv - 2][l4 * 4 + r][ot * 16 + l15] += oacc[ot][r];
    }
    __syncthreads();

    // ---- normalize + store: wave wv handles rows [wv*4, wv*4+4) ----
#pragma unroll
    for (int rr = 0; rr < 4; ++rr) {
        const int n = wv * 4 + rr;
        float inv = 1.0f / (Ls[0][n] + Ls[1][n] + Ls[2][n] + Ls[3][n] + 1e-9f);
        float4 a0 = *(const float4*)&Acc[0][n][lane * 4];
        float4 a1 = *(const float4*)&Acc[1][n][lane * 4];
        float4 o4;
        o4.x = (a0.x + a1.x) * inv;
        o4.y = (a0.y + a1.y) * inv;
        o4.z = (a0.z + a1.z) * inv;
        o4.w = (a0.w + a1.w) * inv;
        *(float4*)&out[(size_t)(nb + n) * O + lane * 4] = o4;
    }
}

extern "C" void kernel_launch(void* const* d_in, const int* in_sizes, int n_in,
                              void* d_out, int out_size, void* d_ws, size_t ws_size,
                              hipStream_t stream) {
    const float* x   = (const float*)d_in[0];  // N x 128
    const float* cen = (const float*)d_in[1];  // 512 x 128
    const float* ls  = (const float*)d_in[2];  // 512
    const float* w   = (const float*)d_in[3];  // 256 x 512
    float* out = (float*)d_out;                // N x 256

    const int N = in_sizes[0] / D;             // 8192
    dim3 grid(N / 16), block(NT);
    hipLaunchKernelGGL(rbf_one, grid, block, 0, stream, x, cen, ls, w, out);
}

// Round 5
// 27.722 us; speedup vs baseline: 1.9571x; 1.9571x over previous
//
#include <hip/hip_runtime.h>

typedef float  f32x4 __attribute__((ext_vector_type(4)));
typedef short  s16x8 __attribute__((ext_vector_type(8)));
typedef ushort u16x8 __attribute__((ext_vector_type(8)));

constexpr int D  = 128;
constexpr int K  = 512;
constexpr int O  = 256;
constexpr int NT = 256;
constexpr float NL2E = -1.44269504088896340736f;  // -log2(e)

__device__ __forceinline__ ushort f2bf(float f) {
    uint u = __builtin_bit_cast(uint, f);
    return (ushort)((u + 0x7FFFu + ((u >> 16) & 1u)) >> 16);
}
__device__ __forceinline__ float bf2f(ushort h) {
    return __builtin_bit_cast(float, ((uint)h) << 16);
}

// ================= prep: fragment-ordered bf16 operands + fused stats =================
// chunk layout: chunk c holds 64 lanes x 8 bf16 (16B/lane, contiguous 1KB).
// X/C: c = (panel16*4 + q)*64 + lane ; elem = src[panel*16 + (lane&15)][q*32 + (lane>>4)*8 + j]
// W:   c = (kslab32*16 + ot)*64 + lane; elem = w[ot*16 + (lane&15)][kslab*32 + (lane>>4)*8 + j]
__global__ __launch_bounds__(NT)
void rbf_prep(const float* __restrict__ x, const float* __restrict__ cen,
              const float* __restrict__ ls, const float* __restrict__ w,
              ushort* __restrict__ Xh, ushort* __restrict__ Xl,
              ushort* __restrict__ Ch, ushort* __restrict__ Cl,
              ushort* __restrict__ Wf, float* __restrict__ xs2,
              float2* __restrict__ ecs, int nxb, int ncb)
{
    __shared__ float red[4][16];
    const int b = blockIdx.x, t = threadIdx.x, lane = t & 63, wq = t >> 6;

    if (b < nxb + ncb) {
        const bool isX  = b < nxb;
        const int panel = isX ? b : (b - nxb);
        const float* src = isX ? x : cen;
        ushort* dh = isX ? Xh : Ch;
        ushort* dl = isX ? Xl : Cl;
        const int row = panel * 16 + (lane & 15);
        const int col = wq * 32 + (lane >> 4) * 8;
        const float* p = src + (size_t)row * D + col;
        float4 v0 = *(const float4*)p, v1 = *(const float4*)(p + 4);
        float f[8] = {v0.x, v0.y, v0.z, v0.w, v1.x, v1.y, v1.z, v1.w};
        u16x8 h, l;
        float s = 0.f;
#pragma unroll
        for (int j = 0; j < 8; ++j) {
            s = fmaf(f[j], f[j], s);
            ushort hb = f2bf(f[j]);
            h[j] = hb;
            l[j] = f2bf(f[j] - bf2f(hb));
        }
        const size_t c = ((size_t)panel * 4 + wq) * 64 + lane;
        *(u16x8*)&dh[c * 8] = h;
        *(u16x8*)&dl[c * 8] = l;
        s += __shfl_xor(s, 16);
        s += __shfl_xor(s, 32);
        if (lane < 16) red[wq][lane] = s;
        __syncthreads();
        if (t < 16) {
            float sum = red[0][t] + red[1][t] + red[2][t] + red[3][t];
            if (isX) {
                xs2[panel * 16 + t] = sum;
            } else {
                int k = panel * 16 + t;
                float e = __expf(2.0f * ls[k]);
                ecs[k] = make_float2(NL2E * e, NL2E * e * sum);
            }
        }
    } else {
        const int c0 = (b - nxb - ncb) * NT + t;
        const int ln = c0 & 63, ot = (c0 >> 6) & 15, ks = c0 >> 10;
        const int o  = ot * 16 + (ln & 15);
        const int kb = ks * 32 + (ln >> 4) * 8;
        const float* p = w + (size_t)o * K + kb;
        float4 v0 = *(const float4*)p, v1 = *(const float4*)(p + 4);
        u16x8 h;
        h[0] = f2bf(v0.x); h[1] = f2bf(v0.y); h[2] = f2bf(v0.z); h[3] = f2bf(v0.w);
        h[4] = f2bf(v1.x); h[5] = f2bf(v1.y); h[6] = f2bf(v1.z); h[7] = f2bf(v1.w);
        *(u16x8*)&Wf[(size_t)c0 * 8] = h;
    }
}

// ================= main: pure-dataflow fused kernel =================
constexpr int PP = 40;   // Ps row stride in ushorts

__global__ __launch_bounds__(NT, 2)
void rbf_main(const ushort* __restrict__ Xh, const ushort* __restrict__ Xl,
              const ushort* __restrict__ Ch, const ushort* __restrict__ Cl,
              const ushort* __restrict__ Wf, const float* __restrict__ xs2,
              const float2* __restrict__ ecs, float* __restrict__ out)
{
    __shared__ ushort Ps[2][4][16][PP];
    __shared__ float  Acc[2][16][O + 4];
    __shared__ float  Ls[4][16];

    const int t = threadIdx.x, lane = t & 63, wv = t >> 6;
    const int l15 = lane & 15, l4 = lane >> 4;
    const int nb = blockIdx.x * 16;

    // X fragments (hoisted; frag-ordered -> base + lane*16B)
    s16x8 xh[4], xl[4];
    {
        const size_t base = ((size_t)blockIdx.x * 4) * 64 + lane;
#pragma unroll
        for (int q = 0; q < 4; ++q) {
            xh[q] = *(const s16x8*)&Xh[(base + q * 64) * 8];
            xl[q] = *(const s16x8*)&Xl[(base + q * 64) * 8];
        }
    }
    const float xs2v = xs2[nb + l15];

    f32x4 oacc[16];
#pragma unroll
    for (int i = 0; i < 16; ++i) oacc[i] = (f32x4){0.f, 0.f, 0.f, 0.f};
    float Lp = 0.f;

    // C fragment double-buffer: one slab (32 kernels) ahead
    s16x8 ch[2][2][4], cl[2][2][4];
#define LOADC(buf, s_) {                                                    \
    _Pragma("unroll") for (int bt = 0; bt < 2; ++bt) {                      \
        const size_t kt = (size_t)(wv * 8 + (s_) * 2 + bt);                 \
        _Pragma("unroll") for (int q = 0; q < 4; ++q) {                     \
            const size_t cc = ((kt * 4 + q) * 64 + lane) * 8;               \
            ch[buf][bt][q] = *(const s16x8*)&Ch[cc];                        \
            cl[buf][bt][q] = *(const s16x8*)&Cl[cc];                        \
        } } }

    LOADC(0, 0);

#pragma unroll
    for (int s = 0; s < 4; ++s) {
        const int cur = s & 1, nxt = cur ^ 1;
        const ushort* wbase = &Wf[((((size_t)(wv * 4 + s)) * 16) * 64 + lane) * 8];

        if (s < 3) LOADC(nxt, s + 1);

        // ---- GEMM1 (swapped: A=C, B=X): D row=kernel, col=data-row ----
#pragma unroll
        for (int bt = 0; bt < 2; ++bt) {
            f32x4 ghh = (f32x4){0.f,0.f,0.f,0.f};
            f32x4 ghl = (f32x4){0.f,0.f,0.f,0.f};
            f32x4 glh = (f32x4){0.f,0.f,0.f,0.f};
#pragma unroll
            for (int q = 0; q < 4; ++q) {
                ghh = __builtin_amdgcn_mfma_f32_16x16x32_bf16(ch[cur][bt][q], xh[q], ghh, 0, 0, 0);
                ghl = __builtin_amdgcn_mfma_f32_16x16x32_bf16(ch[cur][bt][q], xl[q], ghl, 0, 0, 0);
                glh = __builtin_amdgcn_mfma_f32_16x16x32_bf16(cl[cur][bt][q], xh[q], glh, 0, 0, 0);
            }
            f32x4 g = ghh + ghl + glh;

            // lane holds rows(kernels) kbase..kbase+3, col(data row) l15
            const int kbase = wv * 128 + s * 32 + bt * 16 + l4 * 4;
            float4 e0 = *(const float4*)&ecs[kbase];      // (x,y)=ec[0], (z,w)=ec[1]
            float4 e1 = *(const float4*)&ecs[kbase + 2];
            float ph0 = exp2f(fmaf(e0.x, fmaf(-2.f, g[0], xs2v), e0.y));
            float ph1 = exp2f(fmaf(e0.z, fmaf(-2.f, g[1], xs2v), e0.w));
            float ph2 = exp2f(fmaf(e1.x, fmaf(-2.f, g[2], xs2v), e1.y));
            float ph3 = exp2f(fmaf(e1.z, fmaf(-2.f, g[3], xs2v), e1.w));
            Lp += (ph0 + ph1) + (ph2 + ph3);
            uint p0 = (uint)f2bf(ph0) | ((uint)f2bf(ph1) << 16);
            uint p1 = (uint)f2bf(ph2) | ((uint)f2bf(ph3) << 16);
            *(uint2*)&Ps[cur][wv][l15][bt * 16 + l4 * 4] = make_uint2(p0, p1);
        }

        // ---- wave-private transpose read (no barrier) + GEMM2 ----
        s16x8 pa = *(const s16x8*)&Ps[cur][wv][l15][l4 * 8];
#pragma unroll
        for (int ot = 0; ot < 16; ++ot) {
            s16x8 bfr = *(const s16x8*)&wbase[(size_t)ot * 64 * 8];
            oacc[ot] = __builtin_amdgcn_mfma_f32_16x16x32_bf16(pa, bfr, oacc[ot], 0, 0, 0);
        }
    }
#undef LOADC

    // ---- row sums: Lp(lane) is partial for data-row l15 over lane's kernels ----
    {
        float v = Lp;
        v += __shfl_xor(v, 16);
        v += __shfl_xor(v, 32);
        if (lane < 16) Ls[wv][lane] = v;
    }

    // ---- combine 4 wave partials ----
    if (wv < 2) {
#pragma unroll
        for (int ot = 0; ot < 16; ++ot)
#pragma unroll
            for (int r = 0; r < 4; ++r)
                Acc[wv][l4 * 4 + r][ot * 16 + l15] = oacc[ot][r];
    }
    __syncthreads();
    if (wv >= 2) {
#pragma unroll
        for (int ot = 0; ot < 16; ++ot)
#pragma unroll
            for (int r = 0; r < 4; ++r)
                Acc[wv - 2][l4 * 4 + r][ot * 16 + l15] += oacc[ot][r];
    }
    __syncthreads();

    // ---- normalize + store ----
#pragma unroll
    for (int rr = 0; rr < 4; ++rr) {
        const int n = wv * 4 + rr;
        float inv = 1.0f / (Ls[0][n] + Ls[1][n] + Ls[2][n] + Ls[3][n] + 1e-9f);
        float4 a0 = *(const float4*)&Acc[0][n][lane * 4];
        float4 a1 = *(const float4*)&Acc[1][n][lane * 4];
        float4 o4;
        o4.x = (a0.x + a1.x) * inv;
        o4.y = (a0.y + a1.y) * inv;
        o4.z = (a0.z + a1.z) * inv;
        o4.w = (a0.w + a1.w) * inv;
        *(float4*)&out[(size_t)(nb + n) * O + lane * 4] = o4;
    }
}

// ================= fallback (round-4 kernel, known-pass) =================
__global__ __launch_bounds__(NT, 2)
void rbf_fb(const float* __restrict__ x, const float* __restrict__ cen,
            const float* __restrict__ ls, const float* __restrict__ w,
            float* __restrict__ out)
{
    __shared__ ushort Ps[2][4][16][PP];
    __shared__ float  Acc[2][16][O + 4];
    __shared__ float  Ls[4][16];
    const int t = threadIdx.x, lane = t & 63, wv = t >> 6;
    const int l15 = lane & 15, l4 = lane >> 4;
    const int nb = blockIdx.x * 16;

    s16x8 xh[4], xl[4];
    float sx = 0.f;
    {
        const float* xr = x + (size_t)(nb + l15) * D;
#pragma unroll
        for (int q = 0; q < 4; ++q) {
            float4 v0 = *(const float4*)(xr + q * 32 + l4 * 8);
            float4 v1 = *(const float4*)(xr + q * 32 + l4 * 8 + 4);
            float f[8] = {v0.x, v0.y, v0.z, v0.w, v1.x, v1.y, v1.z, v1.w};
            s16x8 h, lo;
#pragma unroll
            for (int j = 0; j < 8; ++j) {
                sx = fmaf(f[j], f[j], sx);
                ushort hb = f2bf(f[j]);
                h[j] = (short)hb; lo[j] = (short)f2bf(f[j] - bf2f(hb));
            }
            xh[q] = h; xl[q] = lo;
        }
    }
    sx += __shfl_xor(sx, 16); sx += __shfl_xor(sx, 32);
    float xs2v[4];
#pragma unroll
    for (int r = 0; r < 4; ++r) xs2v[r] = __shfl(sx, l4 * 4 + r);

    f32x4 oacc[16];
#pragma unroll
    for (int ot = 0; ot < 16; ++ot) oacc[ot] = (f32x4){0.f,0.f,0.f,0.f};
    float Lp[4] = {0.f,0.f,0.f,0.f};
    const int kq = wv * (K / 4);

#pragma unroll
    for (int s = 0; s < 4; ++s) {
        const int k0 = kq + s * 32;
#pragma unroll
        for (int bt = 0; bt < 2; ++bt) {
            const int kk = k0 + bt * 16 + l15;
            const float* cr = cen + (size_t)kk * D;
            s16x8 ch[4], cl[4];
            float sc = 0.f;
#pragma unroll
            for (int q = 0; q < 4; ++q) {
                float4 v0 = *(const float4*)(cr + q * 32 + l4 * 8);
                float4 v1 = *(const float4*)(cr + q * 32 + l4 * 8 + 4);
                float f[8] = {v0.x, v0.y, v0.z, v0.w, v1.x, v1.y, v1.z, v1.w};
                s16x8 h, lo;
#pragma unroll
                for (int j = 0; j < 8; ++j) {
                    sc = fmaf(f[j], f[j], sc);
                    ushort hb = f2bf(f[j]);
                    h[j] = (short)hb; lo[j] = (short)f2bf(f[j] - bf2f(hb));
                }
                ch[q] = h; cl[q] = lo;
            }
            sc += __shfl_xor(sc, 16); sc += __shfl_xor(sc, 32);
            float es_ = __expf(2.0f * ls[kk]);
            f32x4 ghh={0,0,0,0}, ghl={0,0,0,0}, glh={0,0,0,0};
#pragma unroll
            for (int q = 0; q < 4; ++q) {
                ghh = __builtin_amdgcn_mfma_f32_16x16x32_bf16(xh[q], ch[q], ghh, 0,0,0);
                ghl = __builtin_amdgcn_mfma_f32_16x16x32_bf16(xh[q], cl[q], ghl, 0,0,0);
                glh = __builtin_amdgcn_mfma_f32_16x16x32_bf16(xl[q], ch[q], glh, 0,0,0);
            }
            f32x4 gg = ghh + ghl + glh;
#pragma unroll
            for (int r = 0; r < 4; ++r) {
                float r2 = xs2v[r] + sc - 2.0f * gg[r];
                float ph = __expf(-es_ * r2);
                Lp[r] += ph;
                Ps[s & 1][wv][l4 * 4 + r][bt * 16 + l15] = f2bf(ph);
            }
        }
        s16x8 pa = *(const s16x8*)&Ps[s & 1][wv][l15][l4 * 8];
#pragma unroll
        for (int ot = 0; ot < 16; ++ot) {
            const float* wr = w + (size_t)(ot * 16 + l15) * K + k0;
            float4 v0 = *(const float4*)(wr + l4 * 8);
            float4 v1 = *(const float4*)(wr + l4 * 8 + 4);
            s16x8 b;
            b[0]=(short)f2bf(v0.x); b[1]=(short)f2bf(v0.y); b[2]=(short)f2bf(v0.z); b[3]=(short)f2bf(v0.w);
            b[4]=(short)f2bf(v1.x); b[5]=(short)f2bf(v1.y); b[6]=(short)f2bf(v1.z); b[7]=(short)f2bf(v1.w);
            oacc[ot] = __builtin_amdgcn_mfma_f32_16x16x32_bf16(pa, b, oacc[ot], 0,0,0);
        }
    }
#pragma unroll
    for (int r = 0; r < 4; ++r) {
        float v = Lp[r];
        v += __shfl_xor(v, 1); v += __shfl_xor(v, 2);
        v += __shfl_xor(v, 4); v += __shfl_xor(v, 8);
        if (l15 == 0) Ls[wv][l4 * 4 + r] = v;
    }
    if (wv < 2) {
#pragma unroll
        for (int ot = 0; ot < 16; ++ot)
#pragma unroll
            for (int r = 0; r < 4; ++r)
                Acc[wv][l4 * 4 + r][ot * 16 + l15] = oacc[ot][r];
    }
    __syncthreads();
    if (wv >= 2) {
#pragma unroll
        for (int ot = 0; ot < 16; ++ot)
#pragma unroll
            for (int r = 0; r < 4; ++r)
                Acc[wv - 2][l4 * 4 + r][ot * 16 + l15] += oacc[ot][r];
    }
    __syncthreads();
#pragma unroll
    for (int rr = 0; rr < 4; ++rr) {
        const int n = wv * 4 + rr;
        float inv = 1.0f / (Ls[0][n] + Ls[1][n] + Ls[2][n] + Ls[3][n] + 1e-9f);
        float4 a0 = *(const float4*)&Acc[0][n][lane * 4];
        float4 a1 = *(const float4*)&Acc[1][n][lane * 4];
        float4 o4;
        o4.x = (a0.x + a1.x) * inv; o4.y = (a0.y + a1.y) * inv;
        o4.z = (a0.z + a1.z) * inv; o4.w = (a0.w + a1.w) * inv;
        *(float4*)&out[(size_t)(nb + n) * O + lane * 4] = o4;
    }
}

extern "C" void kernel_launch(void* const* d_in, const int* in_sizes, int n_in,
                              void* d_out, int out_size, void* d_ws, size_t ws_size,
                              hipStream_t stream) {
    const float* x   = (const float*)d_in[0];  // N x 128
    const float* cen = (const float*)d_in[1];  // 512 x 128
    const float* ls  = (const float*)d_in[2];  // 512
    const float* w   = (const float*)d_in[3];  // 256 x 512
    float* out = (float*)d_out;                // N x 256
    const int N = in_sizes[0] / D;             // 8192

    size_t oXh = 0;
    size_t oXl = oXh + (size_t)N * D * 2;
    size_t oCh = oXl + (size_t)N * D * 2;
    size_t oCl = oCh + (size_t)K * D * 2;
    size_t oWf = oCl + (size_t)K * D * 2;
    size_t oxs = oWf + (size_t)O * K * 2;
    size_t oec = oxs + (size_t)N * 4;
    size_t need = oec + (size_t)K * 8;

    if (ws_size < need || (N % 16) != 0) {
        dim3 grid(N / 16), block(NT);
        hipLaunchKernelGGL(rbf_fb, grid, block, 0, stream, x, cen, ls, w, out);
        return;
    }

    char* ws = (char*)d_ws;
    ushort* Xh = (ushort*)(ws + oXh);
    ushort* Xl = (ushort*)(ws + oXl);
    ushort* Ch = (ushort*)(ws + oCh);
    ushort* Cl = (ushort*)(ws + oCl);
    ushort* Wf = (ushort*)(ws + oWf);
    float*  xs2 = (float*)(ws + oxs);
    float2* ecs = (float2*)(ws + oec);

    const int nxb = N / 16;                    // 512 X panels
    const int ncb = K / 16;                    // 32 C panels
    const int nwb = (O * K / 8) / NT;          // 64 W blocks
    dim3 pgrid(nxb + ncb + nwb), pblock(NT);
    hipLaunchKernelGGL(rbf_prep, pgrid, pblock, 0, stream,
                       x, cen, ls, w, Xh, Xl, Ch, Cl, Wf, xs2, ecs, nxb, ncb);

    dim3 grid(N / 16), block(NT);
    hipLaunchKernelGGL(rbf_main, grid, block, 0, stream,
                       Xh, Xl, Ch, Cl, Wf, xs2, ecs, out);
}